// Round 1
// baseline (362.208 us; speedup 1.0000x reference)
//
#include <hip/hip_runtime.h>

#define HD 32
#define NHEADS 12
#define HH 56
#define WW 56
#define NN (HH * WW)
#define BB 8
#define CC (HD * NHEADS)
#define TOTAL (BB * CC * NN)
#define QCH 8                 // channels per thread (quarter of head_dim)
#define CHUNKS 32             // 4-wide chunks per block => 128 positions
#define TILE_N (CHUNKS * 4)
#define SCALE 0.17677669529663689f

// block (32,4) = 128 threads. threadIdx.x -> 4-wide position chunk (x0 = n0%56 is
// a multiple of 4 and 56%4==0, so a chunk never crosses a row). threadIdx.y ->
// channel quarter (8 channels). Per (tap-row, channel) the 3 dx taps share one
// 8-float window [x0-2 .. x0+5] loaded as float2+float4+float2 (32B, aligned).
// Zero-padding of the unfold is reproduced by zeroing invalid window elements,
// which makes invalid-tap logits exactly 0 (matching the reference) with no
// per-tap masking in the FMA loops.
__global__ __launch_bounds__(128, 3) void dilate_attn_kernel(
    const float* __restrict__ q,
    const float* __restrict__ k,
    const float* __restrict__ v,
    float* __restrict__ out)
{
    const int tx = threadIdx.x;            // 0..31
    const int qy = threadIdx.y;            // 0..3
    const int n0 = blockIdx.x * TILE_N + tx * 4;
    const int bh = blockIdx.y;
    const int b = bh / NHEADS;
    const int head = bh - b * NHEADS;
    const bool active = (n0 < NN);

    const int y = n0 / WW;
    const int x0 = n0 - y * WW;            // multiple of 4, <= 52
    const bool xlo = (x0 == 0);
    const bool xhi = (x0 == WW - 4);

    const int base0 = (b * CC + head * HD + qy * QCH) * NN;

    __shared__ float4 part[4][CHUNKS][9];  // 18 KiB; 144B row stride -> <=2-way (free)

    // ---- q fragment: 8 channels x 4 positions, float4 loads ----
    float qv[QCH][4];
    if (active) {
#pragma unroll
        for (int d = 0; d < QCH; ++d) {
            const float4 t = *reinterpret_cast<const float4*>(q + base0 + d * NN + n0);
            qv[d][0] = t.x; qv[d][1] = t.y; qv[d][2] = t.z; qv[d][3] = t.w;
        }
    } else {
#pragma unroll
        for (int d = 0; d < QCH; ++d)
#pragma unroll
            for (int j = 0; j < 4; ++j) qv[d][j] = 0.f;
    }

    // ---- QK: partial logits over 9 taps for 4 positions ----
    float lg[9][4];
#pragma unroll
    for (int t = 0; t < 9; ++t)
#pragma unroll
        for (int j = 0; j < 4; ++j) lg[t][j] = 0.f;

#pragma unroll
    for (int r = 0; r < 3; ++r) {
        const int ny = y + (r - 1) * 2;
        const bool rv = active && ((unsigned)ny < HH);
#pragma unroll
        for (int d = 0; d < QCH; ++d) {
            float w[8];
            if (rv) {
                const int si = base0 + d * NN + ny * WW + x0;
                int silo = si - 2;            if (silo < 0) silo = 0;
                int sihi = si + 4;            if (sihi > TOTAL - 2) sihi = TOTAL - 2;
                const float2 lo  = *reinterpret_cast<const float2*>(k + silo);
                const float4 mid = *reinterpret_cast<const float4*>(k + si);
                const float2 hi  = *reinterpret_cast<const float2*>(k + sihi);
                w[0] = lo.x; w[1] = lo.y;
                w[2] = mid.x; w[3] = mid.y; w[4] = mid.z; w[5] = mid.w;
                w[6] = hi.x; w[7] = hi.y;
                if (xlo) { w[0] = 0.f; w[1] = 0.f; }
                if (xhi) { w[6] = 0.f; w[7] = 0.f; }
            } else {
#pragma unroll
                for (int e = 0; e < 8; ++e) w[e] = 0.f;
            }
#pragma unroll
            for (int dx = 0; dx < 3; ++dx)
#pragma unroll
                for (int j = 0; j < 4; ++j)
                    lg[r * 3 + dx][j] = fmaf(qv[d][j], w[dx * 2 + j], lg[r * 3 + dx][j]);
        }
    }

    // ---- combine quarters via LDS ----
#pragma unroll
    for (int t = 0; t < 9; ++t)
        part[qy][tx][t] = make_float4(lg[t][0], lg[t][1], lg[t][2], lg[t][3]);
    __syncthreads();
#pragma unroll
    for (int qq = 1; qq < 4; ++qq) {
        const int oq = (qy + qq) & 3;
#pragma unroll
        for (int t = 0; t < 9; ++t) {
            const float4 p = part[oq][tx][t];
            lg[t][0] += p.x; lg[t][1] += p.y; lg[t][2] += p.z; lg[t][3] += p.w;
        }
    }

    // ---- softmax over 9 taps, per position ----
#pragma unroll
    for (int t = 0; t < 9; ++t)
#pragma unroll
        for (int j = 0; j < 4; ++j) lg[t][j] *= SCALE;
#pragma unroll
    for (int j = 0; j < 4; ++j) {
        float m = lg[0][j];
#pragma unroll
        for (int t = 1; t < 9; ++t) m = fmaxf(m, lg[t][j]);
        float s = 0.f;
#pragma unroll
        for (int t = 0; t < 9; ++t) { const float e = __expf(lg[t][j] - m); lg[t][j] = e; s += e; }
        const float inv = 1.f / s;
#pragma unroll
        for (int t = 0; t < 9; ++t) lg[t][j] *= inv;
    }

    // ---- PV: same windows from v ----
    float acc[QCH][4];
#pragma unroll
    for (int d = 0; d < QCH; ++d)
#pragma unroll
        for (int j = 0; j < 4; ++j) acc[d][j] = 0.f;

#pragma unroll
    for (int r = 0; r < 3; ++r) {
        const int ny = y + (r - 1) * 2;
        const bool rv = active && ((unsigned)ny < HH);
#pragma unroll
        for (int d = 0; d < QCH; ++d) {
            float w[8];
            if (rv) {
                const int si = base0 + d * NN + ny * WW + x0;
                int silo = si - 2;            if (silo < 0) silo = 0;
                int sihi = si + 4;            if (sihi > TOTAL - 2) sihi = TOTAL - 2;
                const float2 lo  = *reinterpret_cast<const float2*>(v + silo);
                const float4 mid = *reinterpret_cast<const float4*>(v + si);
                const float2 hi  = *reinterpret_cast<const float2*>(v + sihi);
                w[0] = lo.x; w[1] = lo.y;
                w[2] = mid.x; w[3] = mid.y; w[4] = mid.z; w[5] = mid.w;
                w[6] = hi.x; w[7] = hi.y;
                if (xlo) { w[0] = 0.f; w[1] = 0.f; }
                if (xhi) { w[6] = 0.f; w[7] = 0.f; }
            } else {
#pragma unroll
                for (int e = 0; e < 8; ++e) w[e] = 0.f;
            }
#pragma unroll
            for (int dx = 0; dx < 3; ++dx)
#pragma unroll
                for (int j = 0; j < 4; ++j)
                    acc[d][j] = fmaf(lg[r * 3 + dx][j], w[dx * 2 + j], acc[d][j]);
        }
    }

    // ---- store: out[b, y, x0+j, head*32 + qy*8 + 0..7] ----
    if (active) {
#pragma unroll
        for (int j = 0; j < 4; ++j) {
            float* ob = out + ((b * HH + y) * WW + (x0 + j)) * CC + head * HD + qy * QCH;
            *reinterpret_cast<float4*>(ob)     = make_float4(acc[0][j], acc[1][j], acc[2][j], acc[3][j]);
            *reinterpret_cast<float4*>(ob + 4) = make_float4(acc[4][j], acc[5][j], acc[6][j], acc[7][j]);
        }
    }
}

extern "C" void kernel_launch(void* const* d_in, const int* in_sizes, int n_in,
                              void* d_out, int out_size, void* d_ws, size_t ws_size,
                              hipStream_t stream) {
    const float* q = (const float*)d_in[0];
    const float* k = (const float*)d_in[1];
    const float* v = (const float*)d_in[2];
    float* out = (float*)d_out;

    dim3 block(CHUNKS, 4);
    dim3 grid((NN + TILE_N - 1) / TILE_N, BB * NHEADS);
    dilate_attn_kernel<<<grid, block, 0, stream>>>(q, k, v, out);
}

// Round 2
// 246.539 us; speedup vs baseline: 1.4692x; 1.4692x over previous
//
#include <hip/hip_runtime.h>

#define HD 32
#define NHEADS 12
#define HH 56
#define WW 56
#define NN (HH * WW)
#define BB 8
#define CC (HD * NHEADS)
#define TOTAL (BB * CC * NN)
#define QCH 8                 // channels per thread (quarter of head_dim)
#define CHUNKS 32             // 4-wide chunks per block => 128 positions
#define TILE_N (CHUNKS * 4)
#define SCALE 0.17677669529663689f

// block (32,4) = 128 threads. threadIdx.x -> 4-wide position chunk (x0 = n0%56 is
// a multiple of 4 and 56%4==0, so a chunk never crosses a row). threadIdx.y ->
// channel quarter (8 channels). Per (tap-row, channel) the 3 dx taps share one
// 8-float window [x0-2 .. x0+5] loaded as float2+float4+float2 (32B, aligned).
// Zero-padding of the unfold is reproduced by zeroing invalid window elements.
//
// NOTE: no min-waves arg in launch_bounds. Round-1 used (128,3) and the
// allocator capped VGPRs at 84 (~512/6) -> ~450B/thread scratch spill ->
// WRITE_SIZE 375MB. Peak live state here is ~110 regs; let it float.
__global__ __launch_bounds__(128) void dilate_attn_kernel(
    const float* __restrict__ q,
    const float* __restrict__ k,
    const float* __restrict__ v,
    float* __restrict__ out)
{
    const int tx = threadIdx.x;            // 0..31
    const int qy = threadIdx.y;            // 0..3
    const int n0 = blockIdx.x * TILE_N + tx * 4;
    const int bh = blockIdx.y;
    const int b = bh / NHEADS;
    const int head = bh - b * NHEADS;
    const bool active = (n0 < NN);

    const int y = n0 / WW;
    const int x0 = n0 - y * WW;            // multiple of 4, <= 52
    const bool xlo = (x0 == 0);
    const bool xhi = (x0 == WW - 4);

    const int base0 = (b * CC + head * HD + qy * QCH) * NN;

    __shared__ float4 part[4][CHUNKS][9];  // 18 KiB; 144B row stride -> <=2-way (free)

    // ---- q fragment: 8 channels x 4 positions, float4 loads ----
    float qv[QCH][4];
    if (active) {
#pragma unroll
        for (int d = 0; d < QCH; ++d) {
            const float4 t = *reinterpret_cast<const float4*>(q + base0 + d * NN + n0);
            qv[d][0] = t.x; qv[d][1] = t.y; qv[d][2] = t.z; qv[d][3] = t.w;
        }
    } else {
#pragma unroll
        for (int d = 0; d < QCH; ++d)
#pragma unroll
            for (int j = 0; j < 4; ++j) qv[d][j] = 0.f;
    }

    // ---- QK: partial logits over 9 taps for 4 positions ----
    float lg[9][4];
#pragma unroll
    for (int t = 0; t < 9; ++t)
#pragma unroll
        for (int j = 0; j < 4; ++j) lg[t][j] = 0.f;

#pragma unroll
    for (int r = 0; r < 3; ++r) {
        const int ny = y + (r - 1) * 2;
        const bool rv = active && ((unsigned)ny < HH);
#pragma unroll
        for (int d = 0; d < QCH; ++d) {
            float w[8];
            if (rv) {
                const int si = base0 + d * NN + ny * WW + x0;
                int silo = si - 2;            if (silo < 0) silo = 0;
                int sihi = si + 4;            if (sihi > TOTAL - 2) sihi = TOTAL - 2;
                const float2 lo  = *reinterpret_cast<const float2*>(k + silo);
                const float4 mid = *reinterpret_cast<const float4*>(k + si);
                const float2 hi  = *reinterpret_cast<const float2*>(k + sihi);
                w[0] = lo.x; w[1] = lo.y;
                w[2] = mid.x; w[3] = mid.y; w[4] = mid.z; w[5] = mid.w;
                w[6] = hi.x; w[7] = hi.y;
                if (xlo) { w[0] = 0.f; w[1] = 0.f; }
                if (xhi) { w[6] = 0.f; w[7] = 0.f; }
            } else {
#pragma unroll
                for (int e = 0; e < 8; ++e) w[e] = 0.f;
            }
#pragma unroll
            for (int dx = 0; dx < 3; ++dx)
#pragma unroll
                for (int j = 0; j < 4; ++j)
                    lg[r * 3 + dx][j] = fmaf(qv[d][j], w[dx * 2 + j], lg[r * 3 + dx][j]);
        }
    }

    // ---- combine quarters via LDS ----
#pragma unroll
    for (int t = 0; t < 9; ++t)
        part[qy][tx][t] = make_float4(lg[t][0], lg[t][1], lg[t][2], lg[t][3]);
    __syncthreads();
#pragma unroll
    for (int qq = 1; qq < 4; ++qq) {
        const int oq = (qy + qq) & 3;
#pragma unroll
        for (int t = 0; t < 9; ++t) {
            const float4 p = part[oq][tx][t];
            lg[t][0] += p.x; lg[t][1] += p.y; lg[t][2] += p.z; lg[t][3] += p.w;
        }
    }

    // ---- softmax over 9 taps, per position ----
#pragma unroll
    for (int t = 0; t < 9; ++t)
#pragma unroll
        for (int j = 0; j < 4; ++j) lg[t][j] *= SCALE;
#pragma unroll
    for (int j = 0; j < 4; ++j) {
        float m = lg[0][j];
#pragma unroll
        for (int t = 1; t < 9; ++t) m = fmaxf(m, lg[t][j]);
        float s = 0.f;
#pragma unroll
        for (int t = 0; t < 9; ++t) { const float e = __expf(lg[t][j] - m); lg[t][j] = e; s += e; }
        const float inv = 1.f / s;
#pragma unroll
        for (int t = 0; t < 9; ++t) lg[t][j] *= inv;
    }

    // ---- PV: same windows from v ----
    float acc[QCH][4];
#pragma unroll
    for (int d = 0; d < QCH; ++d)
#pragma unroll
        for (int j = 0; j < 4; ++j) acc[d][j] = 0.f;

#pragma unroll
    for (int r = 0; r < 3; ++r) {
        const int ny = y + (r - 1) * 2;
        const bool rv = active && ((unsigned)ny < HH);
#pragma unroll
        for (int d = 0; d < QCH; ++d) {
            float w[8];
            if (rv) {
                const int si = base0 + d * NN + ny * WW + x0;
                int silo = si - 2;            if (silo < 0) silo = 0;
                int sihi = si + 4;            if (sihi > TOTAL - 2) sihi = TOTAL - 2;
                const float2 lo  = *reinterpret_cast<const float2*>(v + silo);
                const float4 mid = *reinterpret_cast<const float4*>(v + si);
                const float2 hi  = *reinterpret_cast<const float2*>(v + sihi);
                w[0] = lo.x; w[1] = lo.y;
                w[2] = mid.x; w[3] = mid.y; w[4] = mid.z; w[5] = mid.w;
                w[6] = hi.x; w[7] = hi.y;
                if (xlo) { w[0] = 0.f; w[1] = 0.f; }
                if (xhi) { w[6] = 0.f; w[7] = 0.f; }
            } else {
#pragma unroll
                for (int e = 0; e < 8; ++e) w[e] = 0.f;
            }
#pragma unroll
            for (int dx = 0; dx < 3; ++dx)
#pragma unroll
                for (int j = 0; j < 4; ++j)
                    acc[d][j] = fmaf(lg[r * 3 + dx][j], w[dx * 2 + j], acc[d][j]);
        }
    }

    // ---- store: out[b, y, x0+j, head*32 + qy*8 + 0..7] ----
    if (active) {
#pragma unroll
        for (int j = 0; j < 4; ++j) {
            float* ob = out + ((b * HH + y) * WW + (x0 + j)) * CC + head * HD + qy * QCH;
            *reinterpret_cast<float4*>(ob)     = make_float4(acc[0][j], acc[1][j], acc[2][j], acc[3][j]);
            *reinterpret_cast<float4*>(ob + 4) = make_float4(acc[4][j], acc[5][j], acc[6][j], acc[7][j]);
        }
    }
}

extern "C" void kernel_launch(void* const* d_in, const int* in_sizes, int n_in,
                              void* d_out, int out_size, void* d_ws, size_t ws_size,
                              hipStream_t stream) {
    const float* q = (const float*)d_in[0];
    const float* k = (const float*)d_in[1];
    const float* v = (const float*)d_in[2];
    float* out = (float*)d_out;

    dim3 block(CHUNKS, 4);
    dim3 grid((NN + TILE_N - 1) / TILE_N, BB * NHEADS);
    dilate_attn_kernel<<<grid, block, 0, stream>>>(q, k, v, out);
}

// Round 3
// 223.162 us; speedup vs baseline: 1.6231x; 1.1048x over previous
//
#include <hip/hip_runtime.h>

#define HD 32
#define NHEADS 12
#define HH 56
#define WW 56
#define NN (HH * WW)
#define BB 8
#define CC (HD * NHEADS)
#define SCALE 0.17677669529663689f

// LDS tile layout: [3 tap-rows][60 padded positions][32 channels], float each,
// with quad-level XOR swizzle: the 8 float4-quads of each position row are
// permuted by (quad ^ (p&7)). Row stride is 128B, so without the swizzle all
// lanes of a wave (consecutive p) hit the same bank group on ds_read_b128;
// with it, 8 consecutive lanes cover all 32 banks (conflict-free minimum).
// Positions p=0..59 map to spatial x' = p-2 (2-wide zero pad each side), which
// reproduces torch.nn.Unfold's zero padding: OOB taps give logit 0 / PV 0.
__device__ __forceinline__ int lds_addr(int r, int p, int quad, int lane4) {
    return ((r * 60 + p) << 5) + ((quad ^ (p & 7)) << 2) + lane4;
}

// Stage one array's 3 tap-rows into LDS. 2880 float2 slots: (r, ch, s) with
// s = 0..29 covering positions 2s, 2s+1. Slot s=0 and s=29 are the column
// pads (zeros); OOB rows (ny outside [0,56)) are zeros.
__device__ __forceinline__ void stage_tile(const float* __restrict__ src,
                                           float* lds, int bhbase, int y, int tid) {
#pragma unroll
    for (int j = 0; j < 12; ++j) {
        const int i = tid + j * 256;
        if (i < 2880) {
            const int r   = i / 960;
            const int rem = i - r * 960;
            const int ch  = rem / 30;
            const int s   = rem - ch * 30;
            const int ny  = y + (r - 1) * 2;
            float2 val = make_float2(0.f, 0.f);
            if ((unsigned)ny < HH && s >= 1 && s <= 28) {
                val = *reinterpret_cast<const float2*>(
                    src + bhbase + ch * NN + ny * WW + (2 * s - 2));
            }
            const int p0 = 2 * s;
            lds[lds_addr(r, p0,     ch >> 2, ch & 3)] = val.x;
            lds[lds_addr(r, p0 + 1, ch >> 2, ch & 3)] = val.y;
        }
    }
}

// Block: one (b, head, y). 256 threads = 64 x-lanes x 4 channel-quarters.
// One 23KB LDS buffer reused: k-tile -> partial-logit scratch -> v-tile.
// No min-waves clamp (round-1 lesson); per-thread state is small by design.
__global__ __launch_bounds__(256) void dilate_attn_kernel(
    const float* __restrict__ q,
    const float* __restrict__ k,
    const float* __restrict__ v,
    float* __restrict__ out)
{
    const int tid = threadIdx.x;
    const int x   = tid & 63;              // 0..63 (56..63 idle in compute)
    const int qc  = tid >> 6;              // channel quarter 0..3 (= wave id)
    const int y   = blockIdx.x;            // output row
    const int bh  = blockIdx.y;
    const int b   = bh / NHEADS;
    const int head = bh - b * NHEADS;
    const bool active = (x < WW);
    const int xc = active ? x : (WW - 1);  // clamp so LDS addrs stay in range

    __shared__ float lds[5760];            // 23040 B
    float* part = lds;                     // overlay: [4][64][9] partial logits

    const int bhbase = (b * CC + head * HD) * NN;

    // ---- q fragment: 8 channels, coalesced scalar loads ----
    float qv[8];
    if (active) {
        const float* qb = q + bhbase + (qc * 8) * NN + y * WW + x;
#pragma unroll
        for (int d = 0; d < 8; ++d) qv[d] = qb[d * NN];
    } else {
#pragma unroll
        for (int d = 0; d < 8; ++d) qv[d] = 0.f;
    }

    // ---- stage k tile ----
    stage_tile(k, lds, bhbase, y, tid);
    __syncthreads();

    // ---- QK: partial logits (8 channels) from LDS ----
    float lg[9];
#pragma unroll
    for (int r = 0; r < 3; ++r) {
#pragma unroll
        for (int dxi = 0; dxi < 3; ++dxi) {
            const int p = xc + 2 * dxi;    // spatial x' = x + 2*(dxi-1)
            const float4 A = *reinterpret_cast<const float4*>(&lds[lds_addr(r, p, 2 * qc,     0)]);
            const float4 B = *reinterpret_cast<const float4*>(&lds[lds_addr(r, p, 2 * qc + 1, 0)]);
            float s = 0.f;
            s = fmaf(qv[0], A.x, s); s = fmaf(qv[1], A.y, s);
            s = fmaf(qv[2], A.z, s); s = fmaf(qv[3], A.w, s);
            s = fmaf(qv[4], B.x, s); s = fmaf(qv[5], B.y, s);
            s = fmaf(qv[6], B.z, s); s = fmaf(qv[7], B.w, s);
            lg[r * 3 + dxi] = s;
        }
    }
    __syncthreads();   // all k reads done before overlay write

    // ---- combine quarters via LDS scratch ----
#pragma unroll
    for (int t = 0; t < 9; ++t) part[(qc * 64 + x) * 9 + t] = lg[t];
    __syncthreads();
#pragma unroll
    for (int o = 1; o < 4; ++o) {
        const int oq = (qc + o) & 3;
#pragma unroll
        for (int t = 0; t < 9; ++t) lg[t] += part[(oq * 64 + x) * 9 + t];
    }

    // ---- softmax over 9 taps (in registers, duplicated per quarter) ----
#pragma unroll
    for (int t = 0; t < 9; ++t) lg[t] *= SCALE;
    float m = lg[0];
#pragma unroll
    for (int t = 1; t < 9; ++t) m = fmaxf(m, lg[t]);
    float wsum = 0.f;
#pragma unroll
    for (int t = 0; t < 9; ++t) { lg[t] = __expf(lg[t] - m); wsum += lg[t]; }
    const float inv = 1.f / wsum;
#pragma unroll
    for (int t = 0; t < 9; ++t) lg[t] *= inv;

    __syncthreads();   // all part reads done before v overwrites buffer

    // ---- stage v tile (same buffer, same layout) ----
    stage_tile(v, lds, bhbase, y, tid);
    __syncthreads();

    // ---- PV: 8 output channels from LDS ----
    float acc[8];
#pragma unroll
    for (int d = 0; d < 8; ++d) acc[d] = 0.f;
#pragma unroll
    for (int r = 0; r < 3; ++r) {
#pragma unroll
        for (int dxi = 0; dxi < 3; ++dxi) {
            const int p = xc + 2 * dxi;
            const float w = lg[r * 3 + dxi];
            const float4 A = *reinterpret_cast<const float4*>(&lds[lds_addr(r, p, 2 * qc,     0)]);
            const float4 B = *reinterpret_cast<const float4*>(&lds[lds_addr(r, p, 2 * qc + 1, 0)]);
            acc[0] = fmaf(w, A.x, acc[0]); acc[1] = fmaf(w, A.y, acc[1]);
            acc[2] = fmaf(w, A.z, acc[2]); acc[3] = fmaf(w, A.w, acc[3]);
            acc[4] = fmaf(w, B.x, acc[4]); acc[5] = fmaf(w, B.y, acc[5]);
            acc[6] = fmaf(w, B.z, acc[6]); acc[7] = fmaf(w, B.w, acc[7]);
        }
    }

    // ---- store: out[b, y, x, head*32 + qc*8 + 0..7] ----
    if (active) {
        float* ob = out + ((b * HH + y) * WW + x) * CC + head * HD + qc * 8;
        *reinterpret_cast<float4*>(ob)     = make_float4(acc[0], acc[1], acc[2], acc[3]);
        *reinterpret_cast<float4*>(ob + 4) = make_float4(acc[4], acc[5], acc[6], acc[7]);
    }
}

extern "C" void kernel_launch(void* const* d_in, const int* in_sizes, int n_in,
                              void* d_out, int out_size, void* d_ws, size_t ws_size,
                              hipStream_t stream) {
    const float* q = (const float*)d_in[0];
    const float* k = (const float*)d_in[1];
    const float* v = (const float*)d_in[2];
    float* out = (float*)d_out;

    dim3 block(256);
    dim3 grid(HH, BB * NHEADS);   // one block per (output row, b*head)
    dilate_attn_kernel<<<grid, block, 0, stream>>>(q, k, v, out);
}

// Round 4
// 185.961 us; speedup vs baseline: 1.9478x; 1.2000x over previous
//
#include <hip/hip_runtime.h>

#define HD 32
#define NHEADS 12
#define HH 56
#define WW 56
#define NN (HH * WW)
#define BB 8
#define CC (HD * NHEADS)
#define QCH 8                  // channels per thread (quarter of head_dim)
#define TILE 128               // positions per block = 64 pairs
#define SCALE 0.17677669529663689f

// block (64,4) = 256 threads. tx -> position PAIR (n0 = 2*tx base), qy ->
// channel quarter. P=2 with dilation=2 makes the 3 dx-taps of a row tile
// exactly 6 consecutive floats: three disjoint float2 loads (cols x0-2..x0+3),
// 8B-aligned since x0 is even. Edge taps are all-or-nothing per pair
// (left tap invalid iff x0==0, right iff x0==54), matching the unfold's
// zero-padding with logit exactly 0. No window regs, no LDS staging --
// k/v rows are L2/L3-resident; the only LDS use is the 18KB logit exchange.
// Lessons: P=4 -> register cliff (r1/r2); LDS tile staging -> net tax (r3).
__global__ __launch_bounds__(256) void dilate_attn_kernel(
    const float* __restrict__ q,
    const float* __restrict__ k,
    const float* __restrict__ v,
    float* __restrict__ out)
{
    const int tx = threadIdx.x;            // 0..63 (pair index)
    const int qc = threadIdx.y;            // 0..3
    const int n0 = blockIdx.x * TILE + 2 * tx;
    const int bh = blockIdx.y;
    const int b = bh / NHEADS;
    const int head = bh - b * NHEADS;
    const bool active = (n0 < NN);

    const int y = n0 / WW;                 // pair never crosses a row (n0 even, WW even)
    const int x0 = n0 - y * WW;            // even, 0..54
    const bool xlo = (x0 == 0);
    const bool xhi = (x0 == WW - 2);

    const int base0 = (b * CC + head * HD + qc * QCH) * NN;

    __shared__ float2 part[4][64][9];      // 18432 B logit exchange

    // ---- q fragment: 8 channels x 2 positions (float2, coalesced) ----
    float qv[QCH][2];
    if (active) {
#pragma unroll
        for (int d = 0; d < QCH; ++d) {
            const float2 t = *reinterpret_cast<const float2*>(q + base0 + d * NN + n0);
            qv[d][0] = t.x; qv[d][1] = t.y;
        }
    } else {
#pragma unroll
        for (int d = 0; d < QCH; ++d) { qv[d][0] = 0.f; qv[d][1] = 0.f; }
    }

    // ---- QK: partial logits over 9 taps for 2 positions ----
    float lg[9][2];
#pragma unroll
    for (int t = 0; t < 9; ++t) { lg[t][0] = 0.f; lg[t][1] = 0.f; }

#pragma unroll
    for (int r = 0; r < 3; ++r) {
        const int ny = y + (r - 1) * 2;
        const bool rv = active && ((unsigned)ny < HH);
        const int rowbase = base0 + ny * WW + x0;
#pragma unroll
        for (int d = 0; d < QCH; ++d) {
            const float* kb = k + rowbase + d * NN;
            float2 w0 = make_float2(0.f, 0.f);
            float2 w1 = make_float2(0.f, 0.f);
            float2 w2 = make_float2(0.f, 0.f);
            if (rv) {
                w1 = *reinterpret_cast<const float2*>(kb);
                if (!xlo) w0 = *reinterpret_cast<const float2*>(kb - 2);
                if (!xhi) w2 = *reinterpret_cast<const float2*>(kb + 2);
            }
            lg[r * 3 + 0][0] = fmaf(qv[d][0], w0.x, lg[r * 3 + 0][0]);
            lg[r * 3 + 0][1] = fmaf(qv[d][1], w0.y, lg[r * 3 + 0][1]);
            lg[r * 3 + 1][0] = fmaf(qv[d][0], w1.x, lg[r * 3 + 1][0]);
            lg[r * 3 + 1][1] = fmaf(qv[d][1], w1.y, lg[r * 3 + 1][1]);
            lg[r * 3 + 2][0] = fmaf(qv[d][0], w2.x, lg[r * 3 + 2][0]);
            lg[r * 3 + 2][1] = fmaf(qv[d][1], w2.y, lg[r * 3 + 2][1]);
        }
    }

    // ---- combine quarters via LDS (one barrier total) ----
#pragma unroll
    for (int t = 0; t < 9; ++t) part[qc][tx][t] = make_float2(lg[t][0], lg[t][1]);
    __syncthreads();
#pragma unroll
    for (int o = 1; o < 4; ++o) {
        const int oq = (qc + o) & 3;
#pragma unroll
        for (int t = 0; t < 9; ++t) {
            const float2 p = part[oq][tx][t];
            lg[t][0] += p.x; lg[t][1] += p.y;
        }
    }

    // ---- softmax over 9 taps, per position (dup per quarter; cheap) ----
#pragma unroll
    for (int j = 0; j < 2; ++j) {
        float m = lg[0][j] * SCALE;
#pragma unroll
        for (int t = 0; t < 9; ++t) { lg[t][j] *= SCALE; m = fmaxf(m, lg[t][j]); }
        float s = 0.f;
#pragma unroll
        for (int t = 0; t < 9; ++t) { const float e = __expf(lg[t][j] - m); lg[t][j] = e; s += e; }
        const float inv = 1.f / s;
#pragma unroll
        for (int t = 0; t < 9; ++t) lg[t][j] *= inv;
    }

    // ---- PV: same disjoint float2 taps from v ----
    float acc[QCH][2];
#pragma unroll
    for (int d = 0; d < QCH; ++d) { acc[d][0] = 0.f; acc[d][1] = 0.f; }

#pragma unroll
    for (int r = 0; r < 3; ++r) {
        const int ny = y + (r - 1) * 2;
        const bool rv = active && ((unsigned)ny < HH);
        const int rowbase = base0 + ny * WW + x0;
#pragma unroll
        for (int d = 0; d < QCH; ++d) {
            const float* vb = v + rowbase + d * NN;
            float2 w0 = make_float2(0.f, 0.f);
            float2 w1 = make_float2(0.f, 0.f);
            float2 w2 = make_float2(0.f, 0.f);
            if (rv) {
                w1 = *reinterpret_cast<const float2*>(vb);
                if (!xlo) w0 = *reinterpret_cast<const float2*>(vb - 2);
                if (!xhi) w2 = *reinterpret_cast<const float2*>(vb + 2);
            }
            acc[d][0] = fmaf(lg[r * 3 + 0][0], w0.x, acc[d][0]);
            acc[d][1] = fmaf(lg[r * 3 + 0][1], w0.y, acc[d][1]);
            acc[d][0] = fmaf(lg[r * 3 + 1][0], w1.x, acc[d][0]);
            acc[d][1] = fmaf(lg[r * 3 + 1][1], w1.y, acc[d][1]);
            acc[d][0] = fmaf(lg[r * 3 + 2][0], w2.x, acc[d][0]);
            acc[d][1] = fmaf(lg[r * 3 + 2][1], w2.y, acc[d][1]);
        }
    }

    // ---- store: out[b, y, x0+j, head*32 + qc*8 + 0..7] ----
    if (active) {
#pragma unroll
        for (int j = 0; j < 2; ++j) {
            float* ob = out + ((b * HH + y) * WW + (x0 + j)) * CC + head * HD + qc * QCH;
            *reinterpret_cast<float4*>(ob)     = make_float4(acc[0][j], acc[1][j], acc[2][j], acc[3][j]);
            *reinterpret_cast<float4*>(ob + 4) = make_float4(acc[4][j], acc[5][j], acc[6][j], acc[7][j]);
        }
    }
}

extern "C" void kernel_launch(void* const* d_in, const int* in_sizes, int n_in,
                              void* d_out, int out_size, void* d_ws, size_t ws_size,
                              hipStream_t stream) {
    const float* q = (const float*)d_in[0];
    const float* k = (const float*)d_in[1];
    const float* v = (const float*)d_in[2];
    float* out = (float*)d_out;

    dim3 block(64, 4);
    dim3 grid((NN + TILE - 1) / TILE, BB * NHEADS);
    dilate_attn_kernel<<<grid, block, 0, stream>>>(q, k, v, out);
}